// Round 2
// baseline (104.471 us; speedup 1.0000x reference)
//
#include <hip/hip_runtime.h>
#include <math.h>

// RansacRouting: B=32, I=1152, O=10, D=16, H=10, S=922
// v[b,o,:] == Mu[b,o,:,h*], h* = argmin_h loss.  Mu over subset computed via
// complement (230 elems): num_h = tot - sum_{i in complement_h} vn_i * u_i.
//
// Round 2: fix vmcnt-order serialization. Issue order == consumption order:
// sidx loads (scatter) first, u-row loads second, no barrier in between.
// Scatter fully unrolled (loads then atomics). Mu gather unrolled 4-row
// (2-row halves for VGPR). usq hoisted off the post-Mu critical path.

#define B_    32
#define I_    1152
#define O_    10
#define D_    16
#define H_    10
#define S_    922
#define COMP  230     // I_ - S_
#define MASKW 36      // 1152/32
#define NT    384
#define NW    6       // waves per block
#define RPT   3       // rows per thread: 1152/384

// ---- wave64 sum via DPP (VALU pipe, no LDS) -- result valid in lane 63 ----
template <int CTRL, int ROWM>
static __device__ __forceinline__ float dpp_f(float v) {
    return __int_as_float(__builtin_amdgcn_update_dpp(
        0, __float_as_int(v), CTRL, ROWM, 0xf, true));
}
static __device__ __forceinline__ float wave_sum_f32(float v) {
    v += dpp_f<0x111, 0xf>(v);   // row_shr:1
    v += dpp_f<0x112, 0xf>(v);   // row_shr:2
    v += dpp_f<0x114, 0xf>(v);   // row_shr:4
    v += dpp_f<0x118, 0xf>(v);   // row_shr:8
    v += dpp_f<0x142, 0xa>(v);   // row_bcast15 -> rows 1,3
    v += dpp_f<0x143, 0xc>(v);   // row_bcast31 -> rows 2,3
    return v;                    // lane 63 holds the total
}
template <int CTRL, int ROWM>
static __device__ __forceinline__ double dpp_d(double v) {
    long long x = __double_as_longlong(v);
    int lo = (int)(unsigned)(x & 0xffffffffLL);
    int hi = (int)(x >> 32);
    lo = __builtin_amdgcn_update_dpp(0, lo, CTRL, ROWM, 0xf, true);
    hi = __builtin_amdgcn_update_dpp(0, hi, CTRL, ROWM, 0xf, true);
    return __longlong_as_double((long long)(unsigned)lo | ((long long)hi << 32));
}
static __device__ __forceinline__ double wave_sum_f64(double v) {
    v += dpp_d<0x111, 0xf>(v);
    v += dpp_d<0x112, 0xf>(v);
    v += dpp_d<0x114, 0xf>(v);
    v += dpp_d<0x118, 0xf>(v);
    v += dpp_d<0x142, 0xa>(v);
    v += dpp_d<0x143, 0xc>(v);
    return v;
}

__global__ __launch_bounds__(NT, 3) void ransac_kernel(
    const float* __restrict__ up,      // [B,I,O,D]
    const int*   __restrict__ sidx,    // [B,S,O,H]
    float*       __restrict__ out)     // [B,O,D]
{
    __shared__ unsigned       mask[H_][MASKW];     // 1440 B
    __shared__ int            ccount[H_];          // 40
    __shared__ unsigned short clist[H_][COMP];     // 4600
    __shared__ float          Mu_s[H_][D_];        // 640
    __shared__ float          totred[NW][17];      // 408
    __shared__ float          tot[17];             // [0..15]=sum vn*u_d, [16]=sum vn
    __shared__ double         lpart[H_][NW];       // 480
    __shared__ double         losses[H_];          // 80
    __shared__ int            hstar;

    // XCD-aware mapping: the 10 o-blocks of one b share an XCD (L2 reuse)
    const int blk = blockIdx.x;
    const int xcd = blk & 7, g = blk >> 3;       // g in [0,40)
    const int b   = xcd + 8 * (g / O_);
    const int o   = g - O_ * (g / O_);
    const int bo  = b * O_ + o;

    const int tid  = threadIdx.x;
    const int lane = tid & 63;
    const int wv   = tid >> 6;

    // --- zero masks / counters (single shot: 360 < NT) ---
    if (tid < H_ * MASKW) ((unsigned*)mask)[tid] = 0u;
    if (tid < H_) ccount[tid] = 0;
    __syncthreads();

    // ================= issue order == consumption order =================
    // (1) sidx loads -- consumed first (scatter atomics)
    const int* sb = sidx + (size_t)b * (S_ * O_ * H_) + o * H_;
    const bool p2 = tid < (S_ - 2 * NT);           // tid < 154
    const int2* ps0 = (const int2*)(sb + (size_t)tid * (O_ * H_));
    const int2* ps1 = (const int2*)(sb + (size_t)(tid + NT) * (O_ * H_));
    int2 a0 = ps0[0], a1 = ps0[1], a2 = ps0[2], a3 = ps0[3], a4 = ps0[4];
    int2 b0 = ps1[0], b1 = ps1[1], b2 = ps1[2], b3 = ps1[3], b4 = ps1[4];
    int2 c0 = {0,0}, c1 = {0,0}, c2 = {0,0}, c3 = {0,0}, c4 = {0,0};
    if (p2) {
        const int2* ps2 = (const int2*)(sb + (size_t)(tid + 2 * NT) * (O_ * H_));
        c0 = ps2[0]; c1 = ps2[1]; c2 = ps2[2]; c3 = ps2[3]; c4 = ps2[4];
    }

    // (2) u-row loads -- consumed later (tot phase)
    const float* ub = up + ((size_t)b * I_ * O_ + o) * D_;
    float4 R[RPT][4];
    #pragma unroll
    for (int r = 0; r < RPT; ++r) {
        const float4* p = (const float4*)(ub + (size_t)(tid + r * NT) * (O_ * D_));
        R[r][0] = p[0]; R[r][1] = p[1]; R[r][2] = p[2]; R[r][3] = p[3];
    }

    // (3) scatter atomics -- waits only on sidx loads (older in queue)
    {
        int v0[H_] = {a0.x, a0.y, a1.x, a1.y, a2.x, a2.y, a3.x, a3.y, a4.x, a4.y};
        #pragma unroll
        for (int h = 0; h < H_; ++h)
            atomicOr(&mask[h][v0[h] >> 5], 1u << (v0[h] & 31));
        int v1[H_] = {b0.x, b0.y, b1.x, b1.y, b2.x, b2.y, b3.x, b3.y, b4.x, b4.y};
        #pragma unroll
        for (int h = 0; h < H_; ++h)
            atomicOr(&mask[h][v1[h] >> 5], 1u << (v1[h] & 31));
        if (p2) {
            int v2[H_] = {c0.x, c0.y, c1.x, c1.y, c2.x, c2.y, c3.x, c3.y, c4.x, c4.y};
            #pragma unroll
            for (int h = 0; h < H_; ++h)
                atomicOr(&mask[h][v2[h] >> 5], 1u << (v2[h] & 31));
        }
    }

    // (4) tot = sum_i vn_i * u_i  (drains u loads) ---
    float acc[17];
    #pragma unroll
    for (int d = 0; d < 17; ++d) acc[d] = 0.f;
    #pragma unroll
    for (int r = 0; r < RPT; ++r) {
        float4 q0 = R[r][0], q1 = R[r][1], q2 = R[r][2], q3 = R[r][3];
        float s = q0.x*q0.x + q0.y*q0.y + q0.z*q0.z + q0.w*q0.w
                + q1.x*q1.x + q1.y*q1.y + q1.z*q1.z + q1.w*q1.w
                + q2.x*q2.x + q2.y*q2.y + q2.z*q2.z + q2.w*q2.w
                + q3.x*q3.x + q3.y*q3.y + q3.z*q3.z + q3.w*q3.w;
        float vn = sqrtf(s);
        acc[ 0] = fmaf(vn, q0.x, acc[ 0]); acc[ 1] = fmaf(vn, q0.y, acc[ 1]);
        acc[ 2] = fmaf(vn, q0.z, acc[ 2]); acc[ 3] = fmaf(vn, q0.w, acc[ 3]);
        acc[ 4] = fmaf(vn, q1.x, acc[ 4]); acc[ 5] = fmaf(vn, q1.y, acc[ 5]);
        acc[ 6] = fmaf(vn, q1.z, acc[ 6]); acc[ 7] = fmaf(vn, q1.w, acc[ 7]);
        acc[ 8] = fmaf(vn, q2.x, acc[ 8]); acc[ 9] = fmaf(vn, q2.y, acc[ 9]);
        acc[10] = fmaf(vn, q2.z, acc[10]); acc[11] = fmaf(vn, q2.w, acc[11]);
        acc[12] = fmaf(vn, q3.x, acc[12]); acc[13] = fmaf(vn, q3.y, acc[13]);
        acc[14] = fmaf(vn, q3.z, acc[14]); acc[15] = fmaf(vn, q3.w, acc[15]);
        acc[16] += vn;
    }
    #pragma unroll
    for (int d = 0; d < 17; ++d) acc[d] = wave_sum_f32(acc[d]);
    if (lane == 63) {
        #pragma unroll
        for (int d = 0; d < 17; ++d) totred[wv][d] = acc[d];
    }

    // usq precompute (u-only; off the post-Mu critical path)
    float usq[RPT];
    #pragma unroll
    for (int r = 0; r < RPT; ++r) {
        float4 q0 = R[r][0], q1 = R[r][1], q2 = R[r][2], q3 = R[r][3];
        float uq[D_] = {q0.x,q0.y,q0.z,q0.w, q1.x,q1.y,q1.z,q1.w,
                        q2.x,q2.y,q2.z,q2.w, q3.x,q3.y,q3.z,q3.w};
        float s = 0.f;
        #pragma unroll
        for (int d = 0; d < D_; ++d) s = fmaf(uq[d], uq[d], s);
        usq[r] = s;
    }
    __syncthreads();   // masks + totred complete

    if (tid < 17) {
        float t = 0.f;
        #pragma unroll
        for (int w = 0; w < NW; ++w) t += totred[w][tid];
        tot[tid] = t;
    }

    // --- extract complement index lists (230 per h) ---
    for (int h = wv; h < H_; h += NW) {
        if (lane < MASKW) {
            unsigned m = ~mask[h][lane];
            int cnt = __popc(m);
            int base = atomicAdd(&ccount[h], cnt);
            while (m) {
                int bit = __ffs(m) - 1;
                m &= m - 1u;
                clist[h][base++] = (unsigned short)((lane << 5) + bit);
            }
        }
    }
    __syncthreads();   // clist + tot ready

    // --- Mu per hypothesis: unrolled 4-row complement gather (L2-hot) ---
    for (int h = wv; h < H_; h += NW) {
        int i0 = clist[h][lane];
        int i1 = clist[h][lane + 64];
        int i2 = clist[h][lane + 128];
        const bool p3 = lane < (COMP - 192);       // 38 lanes
        int i3 = p3 ? clist[h][lane + 192] : i0;   // safe dup addr, weight 0
        const float w3 = p3 ? 1.f : 0.f;

        float na[17];
        #pragma unroll
        for (int d = 0; d < 17; ++d) na[d] = 0.f;

        auto accum = [&](const float4* p, float w) {
            float4 q0 = p[0], q1 = p[1], q2 = p[2], q3 = p[3];
            float s = q0.x*q0.x + q0.y*q0.y + q0.z*q0.z + q0.w*q0.w
                    + q1.x*q1.x + q1.y*q1.y + q1.z*q1.z + q1.w*q1.w
                    + q2.x*q2.x + q2.y*q2.y + q2.z*q2.z + q2.w*q2.w
                    + q3.x*q3.x + q3.y*q3.y + q3.z*q3.z + q3.w*q3.w;
            float vn = sqrtf(s) * w;
            na[ 0] = fmaf(vn, q0.x, na[ 0]); na[ 1] = fmaf(vn, q0.y, na[ 1]);
            na[ 2] = fmaf(vn, q0.z, na[ 2]); na[ 3] = fmaf(vn, q0.w, na[ 3]);
            na[ 4] = fmaf(vn, q1.x, na[ 4]); na[ 5] = fmaf(vn, q1.y, na[ 5]);
            na[ 6] = fmaf(vn, q1.z, na[ 6]); na[ 7] = fmaf(vn, q1.w, na[ 7]);
            na[ 8] = fmaf(vn, q2.x, na[ 8]); na[ 9] = fmaf(vn, q2.y, na[ 9]);
            na[10] = fmaf(vn, q2.z, na[10]); na[11] = fmaf(vn, q2.w, na[11]);
            na[12] = fmaf(vn, q3.x, na[12]); na[13] = fmaf(vn, q3.y, na[13]);
            na[14] = fmaf(vn, q3.z, na[14]); na[15] = fmaf(vn, q3.w, na[15]);
            na[16] += vn;
        };

        // two 2-row halves: issue both rows' loads, then accumulate (VGPR-bounded)
        const float4* q0p = (const float4*)(ub + (size_t)i0 * (O_ * D_));
        const float4* q1p = (const float4*)(ub + (size_t)i1 * (O_ * D_));
        accum(q0p, 1.f);
        accum(q1p, 1.f);
        const float4* q2p = (const float4*)(ub + (size_t)i2 * (O_ * D_));
        const float4* q3p = (const float4*)(ub + (size_t)i3 * (O_ * D_));
        accum(q2p, 1.f);
        accum(q3p, w3);

        #pragma unroll
        for (int d = 0; d < 17; ++d) na[d] = wave_sum_f32(na[d]);
        if (lane == 63) {
            float rd = 1.f / (tot[16] - na[16]);
            #pragma unroll
            for (int d = 0; d < D_; ++d)
                Mu_s[h][d] = (tot[d] - na[d]) * rd;
        }
    }
    __syncthreads();   // Mu ready

    // --- loss: h-outer over register-resident rows; Mu broadcast from LDS ---
    for (int h = 0; h < H_; ++h) {
        float4 m0 = *(const float4*)&Mu_s[h][0];
        float4 m1 = *(const float4*)&Mu_s[h][4];
        float4 m2 = *(const float4*)&Mu_s[h][8];
        float4 m3 = *(const float4*)&Mu_s[h][12];
        float mv[D_] = {m0.x, m0.y, m0.z, m0.w, m1.x, m1.y, m1.z, m1.w,
                        m2.x, m2.y, m2.z, m2.w, m3.x, m3.y, m3.z, m3.w};
        float musq = 0.f;
        #pragma unroll
        for (int d = 0; d < D_; ++d) musq = fmaf(mv[d], mv[d], musq);
        double l = 0.0;
        #pragma unroll
        for (int r = 0; r < RPT; ++r) {
            float uq[D_] = {R[r][0].x, R[r][0].y, R[r][0].z, R[r][0].w,
                            R[r][1].x, R[r][1].y, R[r][1].z, R[r][1].w,
                            R[r][2].x, R[r][2].y, R[r][2].z, R[r][2].w,
                            R[r][3].x, R[r][3].y, R[r][3].z, R[r][3].w};
            float dot = 0.f;
            #pragma unroll
            for (int d = 0; d < D_; ++d) dot = fmaf(uq[d], mv[d], dot);
            float d2 = fmaf(-2.f, dot, usq[r] + musq);
            l += (double)sqrtf(fmaxf(d2, 0.f));
        }
        l = wave_sum_f64(l);
        if (lane == 63) lpart[h][wv] = l;
    }
    __syncthreads();

    if (tid < H_) {
        double t = 0.0;
        #pragma unroll
        for (int w = 0; w < NW; ++w) t += lpart[tid][w];
        losses[tid] = t;
    }
    __syncthreads();
    if (tid == 0) {
        int best = 0; double bl = losses[0];
        #pragma unroll
        for (int h = 1; h < H_; ++h)
            if (losses[h] < bl) { bl = losses[h]; best = h; }
        hstar = best;
    }
    __syncthreads();
    if (tid < D_)
        out[(size_t)bo * D_ + tid] = Mu_s[hstar][tid];
}

extern "C" void kernel_launch(void* const* d_in, const int* in_sizes, int n_in,
                              void* d_out, int out_size, void* d_ws, size_t ws_size,
                              hipStream_t stream) {
    const float* up   = (const float*)d_in[0];
    const int*   sidx = (const int*)d_in[1];
    float*       out  = (float*)d_out;
    ransac_kernel<<<B_ * O_, NT, 0, stream>>>(up, sidx, out);
}

// Round 4
// 104.358 us; speedup vs baseline: 1.0011x; 1.0011x over previous
//
#include <hip/hip_runtime.h>
#include <math.h>

// RansacRouting: B=32, I=1152, O=10, D=16, H=10, S=922
// v[b,o,:] == Mu[b,o,:,h*], h* = argmin_h loss.
// Round 3 (resubmit; infra failed): NO complement gather. Mu's complement
// sum computed by a masked full scan over register-resident rows (mask bit
// -> weight 0), DPP-reduced per h. tot is hypothesis #10 (weight always vn).
// Removes ~2300 scattered L2 line-requests/block + the clist extraction
// phase (L2-request-rate was the measured bottleneck: VALUBusy 17%, occ 9%,
// HBM 5%).

#define B_    32
#define I_    1152
#define O_    10
#define D_    16
#define H_    10
#define S_    922
#define MASKW 36      // 1152/32
#define NT    384
#define NW    6       // waves per block
#define RPT   3       // rows per thread: 1152/384
#define HH    11      // 10 hypotheses + 1 "all rows" (tot)

// ---- wave64 sum via DPP (VALU pipe, no LDS) -- result valid in lane 63 ----
template <int CTRL, int ROWM>
static __device__ __forceinline__ float dpp_f(float v) {
    return __int_as_float(__builtin_amdgcn_update_dpp(
        0, __float_as_int(v), CTRL, ROWM, 0xf, true));
}
static __device__ __forceinline__ float wave_sum_f32(float v) {
    v += dpp_f<0x111, 0xf>(v);   // row_shr:1
    v += dpp_f<0x112, 0xf>(v);   // row_shr:2
    v += dpp_f<0x114, 0xf>(v);   // row_shr:4
    v += dpp_f<0x118, 0xf>(v);   // row_shr:8
    v += dpp_f<0x142, 0xa>(v);   // row_bcast15 -> rows 1,3
    v += dpp_f<0x143, 0xc>(v);   // row_bcast31 -> rows 2,3
    return v;                    // lane 63 holds the total
}
template <int CTRL, int ROWM>
static __device__ __forceinline__ double dpp_d(double v) {
    long long x = __double_as_longlong(v);
    int lo = (int)(unsigned)(x & 0xffffffffLL);
    int hi = (int)(x >> 32);
    lo = __builtin_amdgcn_update_dpp(0, lo, CTRL, ROWM, 0xf, true);
    hi = __builtin_amdgcn_update_dpp(0, hi, CTRL, ROWM, 0xf, true);
    return __longlong_as_double((long long)(unsigned)lo | ((long long)hi << 32));
}
static __device__ __forceinline__ double wave_sum_f64(double v) {
    v += dpp_d<0x111, 0xf>(v);
    v += dpp_d<0x112, 0xf>(v);
    v += dpp_d<0x114, 0xf>(v);
    v += dpp_d<0x118, 0xf>(v);
    v += dpp_d<0x142, 0xa>(v);
    v += dpp_d<0x143, 0xc>(v);
    return v;
}

__global__ __launch_bounds__(NT, 3) void ransac_kernel(
    const float* __restrict__ up,      // [B,I,O,D]
    const int*   __restrict__ sidx,    // [B,S,O,H]
    float*       __restrict__ out)     // [B,O,D]
{
    __shared__ unsigned                 mask[H_][MASKW];    // 1440 B
    __shared__ __align__(16) float      hred[HH][NW][20];   // 5280 B
    __shared__ float                    Mu_s[H_][D_];       // 640
    __shared__ double                   lpart[H_][NW];      // 480
    __shared__ double                   losses[H_];         // 80
    __shared__ int                      hstar;

    // XCD-aware mapping: the 10 o-blocks of one b share an XCD (L2 reuse)
    const int blk = blockIdx.x;
    const int xcd = blk & 7, g = blk >> 3;       // g in [0,40)
    const int b   = xcd + 8 * (g / O_);
    const int o   = g - O_ * (g / O_);
    const int bo  = b * O_ + o;

    const int tid  = threadIdx.x;
    const int lane = tid & 63;
    const int wv   = tid >> 6;

    // --- zero masks (360 < NT: single shot) ---
    if (tid < H_ * MASKW) ((unsigned*)mask)[tid] = 0u;
    __syncthreads();

    // ================= issue order == consumption order =================
    // (1) sidx loads -- consumed first (scatter atomics)
    const int* sb = sidx + (size_t)b * (S_ * O_ * H_) + o * H_;
    const bool p2 = tid < (S_ - 2 * NT);           // tid < 154
    const int2* ps0 = (const int2*)(sb + (size_t)tid * (O_ * H_));
    const int2* ps1 = (const int2*)(sb + (size_t)(tid + NT) * (O_ * H_));
    int2 a0 = ps0[0], a1 = ps0[1], a2 = ps0[2], a3 = ps0[3], a4 = ps0[4];
    int2 b0 = ps1[0], b1 = ps1[1], b2 = ps1[2], b3 = ps1[3], b4 = ps1[4];
    int2 c0 = {0,0}, c1 = {0,0}, c2 = {0,0}, c3 = {0,0}, c4 = {0,0};
    if (p2) {
        const int2* ps2 = (const int2*)(sb + (size_t)(tid + 2 * NT) * (O_ * H_));
        c0 = ps2[0]; c1 = ps2[1]; c2 = ps2[2]; c3 = ps2[3]; c4 = ps2[4];
    }

    // (2) u-row loads -- consumed later (vn/scan phases)
    const float* ub = up + ((size_t)b * I_ * O_ + o) * D_;
    float4 R[RPT][4];
    #pragma unroll
    for (int r = 0; r < RPT; ++r) {
        const float4* p = (const float4*)(ub + (size_t)(tid + r * NT) * (O_ * D_));
        R[r][0] = p[0]; R[r][1] = p[1]; R[r][2] = p[2]; R[r][3] = p[3];
    }

    // (3) scatter atomics -- waits only on sidx loads (older in queue)
    {
        int v0[H_] = {a0.x, a0.y, a1.x, a1.y, a2.x, a2.y, a3.x, a3.y, a4.x, a4.y};
        #pragma unroll
        for (int h = 0; h < H_; ++h)
            atomicOr(&mask[h][v0[h] >> 5], 1u << (v0[h] & 31));
        int v1[H_] = {b0.x, b0.y, b1.x, b1.y, b2.x, b2.y, b3.x, b3.y, b4.x, b4.y};
        #pragma unroll
        for (int h = 0; h < H_; ++h)
            atomicOr(&mask[h][v1[h] >> 5], 1u << (v1[h] & 31));
        if (p2) {
            int v2[H_] = {c0.x, c0.y, c1.x, c1.y, c2.x, c2.y, c3.x, c3.y, c4.x, c4.y};
            #pragma unroll
            for (int h = 0; h < H_; ++h)
                atomicOr(&mask[h][v2[h] >> 5], 1u << (v2[h] & 31));
        }
    }

    // (4) vn + usq per register row (drains u loads under the atomics)
    float vn[RPT], usq[RPT];
    #pragma unroll
    for (int r = 0; r < RPT; ++r) {
        float4 q0 = R[r][0], q1 = R[r][1], q2 = R[r][2], q3 = R[r][3];
        float s = q0.x*q0.x + q0.y*q0.y + q0.z*q0.z + q0.w*q0.w
                + q1.x*q1.x + q1.y*q1.y + q1.z*q1.z + q1.w*q1.w
                + q2.x*q2.x + q2.y*q2.y + q2.z*q2.z + q2.w*q2.w
                + q3.x*q3.x + q3.y*q3.y + q3.z*q3.z + q3.w*q3.w;
        vn[r] = sqrtf(s);
        float uq[D_] = {q0.x,q0.y,q0.z,q0.w, q1.x,q1.y,q1.z,q1.w,
                        q2.x,q2.y,q2.z,q2.w, q3.x,q3.y,q3.z,q3.w};
        float t = 0.f;
        #pragma unroll
        for (int d = 0; d < D_; ++d) t = fmaf(uq[d], uq[d], t);
        usq[r] = t;
    }
    __syncthreads();   // masks complete

    // --- masked scan: h<10 -> complement sums; h==10 -> tot (all rows) ---
    const int      w0   = tid >> 5;            // base mask word for row tid
    const unsigned bitm = 1u << (tid & 31);
    for (int h = 0; h < HH; ++h) {
        float na[17];
        #pragma unroll
        for (int d = 0; d < 17; ++d) na[d] = 0.f;
        #pragma unroll
        for (int r = 0; r < RPT; ++r) {
            float w = vn[r];
            if (h < H_) {
                unsigned mw = mask[h][w0 + 12 * r];
                w = (mw & bitm) ? 0.f : w;     // sampled row -> excluded
            }
            float4 q0 = R[r][0], q1 = R[r][1], q2 = R[r][2], q3 = R[r][3];
            na[ 0] = fmaf(w, q0.x, na[ 0]); na[ 1] = fmaf(w, q0.y, na[ 1]);
            na[ 2] = fmaf(w, q0.z, na[ 2]); na[ 3] = fmaf(w, q0.w, na[ 3]);
            na[ 4] = fmaf(w, q1.x, na[ 4]); na[ 5] = fmaf(w, q1.y, na[ 5]);
            na[ 6] = fmaf(w, q1.z, na[ 6]); na[ 7] = fmaf(w, q1.w, na[ 7]);
            na[ 8] = fmaf(w, q2.x, na[ 8]); na[ 9] = fmaf(w, q2.y, na[ 9]);
            na[10] = fmaf(w, q2.z, na[10]); na[11] = fmaf(w, q2.w, na[11]);
            na[12] = fmaf(w, q3.x, na[12]); na[13] = fmaf(w, q3.y, na[13]);
            na[14] = fmaf(w, q3.z, na[14]); na[15] = fmaf(w, q3.w, na[15]);
            na[16] += w;
        }
        #pragma unroll
        for (int d = 0; d < 17; ++d) na[d] = wave_sum_f32(na[d]);
        if (lane == 63) {
            *(float4*)&hred[h][wv][ 0] = make_float4(na[ 0], na[ 1], na[ 2], na[ 3]);
            *(float4*)&hred[h][wv][ 4] = make_float4(na[ 4], na[ 5], na[ 6], na[ 7]);
            *(float4*)&hred[h][wv][ 8] = make_float4(na[ 8], na[ 9], na[10], na[11]);
            *(float4*)&hred[h][wv][12] = make_float4(na[12], na[13], na[14], na[15]);
            hred[h][wv][16] = na[16];
        }
    }
    __syncthreads();   // hred complete

    // --- Mu finalize: Mu_h[d] = (tot[d]-na_h[d]) / (tot[16]-na_h[16]) ---
    for (int h = wv; h < H_; h += NW) {
        if (lane < D_) {
            float naj = 0.f, totj = 0.f, na16 = 0.f, tot16 = 0.f;
            #pragma unroll
            for (int w = 0; w < NW; ++w) {
                naj   += hred[h ][w][lane];
                totj  += hred[10][w][lane];
                na16  += hred[h ][w][16];
                tot16 += hred[10][w][16];
            }
            float rd = 1.f / (tot16 - na16);
            Mu_s[h][lane] = (totj - naj) * rd;
        }
    }
    __syncthreads();   // Mu ready

    // --- loss: h-outer over register-resident rows; Mu broadcast from LDS ---
    for (int h = 0; h < H_; ++h) {
        float4 m0 = *(const float4*)&Mu_s[h][0];
        float4 m1 = *(const float4*)&Mu_s[h][4];
        float4 m2 = *(const float4*)&Mu_s[h][8];
        float4 m3 = *(const float4*)&Mu_s[h][12];
        float mv[D_] = {m0.x, m0.y, m0.z, m0.w, m1.x, m1.y, m1.z, m1.w,
                        m2.x, m2.y, m2.z, m2.w, m3.x, m3.y, m3.z, m3.w};
        float musq = 0.f;
        #pragma unroll
        for (int d = 0; d < D_; ++d) musq = fmaf(mv[d], mv[d], musq);
        double l = 0.0;
        #pragma unroll
        for (int r = 0; r < RPT; ++r) {
            float uq[D_] = {R[r][0].x, R[r][0].y, R[r][0].z, R[r][0].w,
                            R[r][1].x, R[r][1].y, R[r][1].z, R[r][1].w,
                            R[r][2].x, R[r][2].y, R[r][2].z, R[r][2].w,
                            R[r][3].x, R[r][3].y, R[r][3].z, R[r][3].w};
            float dot = 0.f;
            #pragma unroll
            for (int d = 0; d < D_; ++d) dot = fmaf(uq[d], mv[d], dot);
            float d2 = fmaf(-2.f, dot, usq[r] + musq);
            l += (double)sqrtf(fmaxf(d2, 0.f));
        }
        l = wave_sum_f64(l);
        if (lane == 63) lpart[h][wv] = l;
    }
    __syncthreads();

    if (tid < H_) {
        double t = 0.0;
        #pragma unroll
        for (int w = 0; w < NW; ++w) t += lpart[tid][w];
        losses[tid] = t;
    }
    __syncthreads();
    if (tid == 0) {
        int best = 0; double bl = losses[0];
        #pragma unroll
        for (int h = 1; h < H_; ++h)
            if (losses[h] < bl) { bl = losses[h]; best = h; }
        hstar = best;
    }
    __syncthreads();
    if (tid < D_)
        out[(size_t)bo * D_ + tid] = Mu_s[hstar][tid];
}

extern "C" void kernel_launch(void* const* d_in, const int* in_sizes, int n_in,
                              void* d_out, int out_size, void* d_ws, size_t ws_size,
                              hipStream_t stream) {
    const float* up   = (const float*)d_in[0];
    const int*   sidx = (const int*)d_in[1];
    float*       out  = (float*)d_out;
    ransac_kernel<<<B_ * O_, NT, 0, stream>>>(up, sidx, out);
}